// Round 1
// baseline (133.486 us; speedup 1.0000x reference)
//
#include <hip/hip_runtime.h>
#include <math.h>

#define Bsz  2
#define Cch  16
#define Hdim 256
#define Wdim 256
#define HW   (Hdim * Wdim)
#define BHW  (Bsz * HW)
#define CctxN 64
#define NS   4            // g-segments
#define SG   (Hdim / NS)  // 64 g values per segment
#define TH   8            // h rows per block (was 4): halves kv-column re-reads
#define NHT  (Hdim / TH)  // 32 h-tiles
#define LOG2E 1.44269504088896340736f

// exp2f lowers to v_exp_f32 on amdgcn (HW exp is base-2).
__device__ __forceinline__ float fexp2(float x) { return exp2f(x); }

// Kernel 1: projections. 2 hw per thread, float2 loads. q pre-scaled by log2e.
// kv packs (k0, k1, v, 0) per position for one-dwordx4 column loads in attn.
__global__ __launch_bounds__(256) void qkv_kernel(
    const float* __restrict__ x, const float* __restrict__ y,
    const float* __restrict__ Wq, const float* __restrict__ bq,
    const float* __restrict__ Wk, const float* __restrict__ bk,
    const float* __restrict__ Wv, const float* __restrict__ bv,
    float2* __restrict__ qpk, float4* __restrict__ kv) {
  int idx0 = (blockIdx.x * blockDim.x + threadIdx.x) * 2;  // b*HW + hw, even
  int b  = idx0 >> 16;
  int hw = idx0 & (HW - 1);
  const float2* xp = (const float2*)(x + (size_t)b * Cch * HW + hw);
  float q0a = bq[0], q1a = bq[1], k0a = bk[0], k1a = bk[1];
  float q0b = bq[0], q1b = bq[1], k0b = bk[0], k1b = bk[1];
#pragma unroll
  for (int c = 0; c < Cch; c++) {
    float2 xv = xp[c * (HW / 2)];
    q0a = fmaf(Wq[c],       xv.x, q0a);  q0b = fmaf(Wq[c],       xv.y, q0b);
    q1a = fmaf(Wq[Cch + c], xv.x, q1a);  q1b = fmaf(Wq[Cch + c], xv.y, q1b);
    k0a = fmaf(Wk[c],       xv.x, k0a);  k0b = fmaf(Wk[c],       xv.y, k0b);
    k1a = fmaf(Wk[Cch + c], xv.x, k1a);  k1b = fmaf(Wk[Cch + c], xv.y, k1b);
  }
  qpk[idx0]     = make_float2(q0a * LOG2E, q1a * LOG2E);
  qpk[idx0 + 1] = make_float2(q0b * LOG2E, q1b * LOG2E);
  const float2* yp = (const float2*)(y + (size_t)b * CctxN * HW + hw);
  float va = bv[0], vb2 = bv[0];
#pragma unroll
  for (int c = 0; c < CctxN; c++) {
    float2 yv = yp[c * (HW / 2)];
    va  = fmaf(Wv[c], yv.x, va);
    vb2 = fmaf(Wv[c], yv.y, vb2);
  }
  kv[idx0]     = make_float4(k0a, k1a, va,  0.f);
  kv[idx0 + 1] = make_float4(k0b, k1b, vb2, 0.f);
}

// Kernel 2: partial criss-cross softmax sums (no max-sub: scores bounded).
// Block = (b, h-tile of TH=8, g-segment of SG). Thread = w. Diagonal handled
// by post-loop subtraction (no per-iter mask). Row kv in LDS (broadcast
// reads). Column kv load is shared across all TH rows -> TH=8 halves the L2
// column traffic vs TH=4 (total = B*H*W*16B*(H/TH)).
// Partials packed (Z, nH, nW, 0) -> single dwordx4 store per h_l.
__global__ __launch_bounds__(256) void attn_kernel(
    const float2* __restrict__ qpk, const float4* __restrict__ kv,
    float4* __restrict__ part) {
  int s  = blockIdx.x & (NS - 1);
  int ht = (blockIdx.x >> 2) & (NHT - 1);
  int b  = blockIdx.x >> 7;           // 2 (NS) + 5 (NHT) bits
  int w  = threadIdx.x;
  int h0 = ht * TH;
  int g0 = s * SG;
  size_t bbase = (size_t)b * HW;

  __shared__ float4 rowkv[TH][SG];
  {
    int h_l = threadIdx.x >> 6, gg = threadIdx.x & 63;  // stages 2 rows/thread
    rowkv[h_l][gg]     = kv[bbase + (size_t)(h0 + h_l) * Wdim + g0 + gg];
    rowkv[h_l + 4][gg] = kv[bbase + (size_t)(h0 + h_l + 4) * Wdim + g0 + gg];
  }
  float q0[TH], q1[TH];
#pragma unroll
  for (int h_l = 0; h_l < TH; h_l++) {
    float2 qq = qpk[bbase + (size_t)(h0 + h_l) * Wdim + w];
    q0[h_l] = qq.x; q1[h_l] = qq.y;
  }
  __syncthreads();

  float Z[TH], nH[TH], nW[TH];
#pragma unroll
  for (int h_l = 0; h_l < TH; h_l++) { Z[h_l] = 0.f; nH[h_l] = 0.f; nW[h_l] = 0.f; }
#pragma unroll 2
  for (int gg = 0; gg < SG; gg++) {
    float4 kc = kv[bbase + (size_t)(g0 + gg) * Wdim + w];
#pragma unroll
    for (int h_l = 0; h_l < TH; h_l++) {
      float4 r = rowkv[h_l][gg];
      float pH = fexp2(fmaf(q0[h_l], kc.x, q1[h_l] * kc.y));
      float pW = fexp2(fmaf(q0[h_l], r.x,  q1[h_l] * r.y));
      Z [h_l] += pH + pW;
      nH[h_l] = fmaf(pH, kc.z, nH[h_l]);
      nW[h_l] = fmaf(pW, r.z,  nW[h_l]);
    }
  }
  // Diagonal fixup: subtract the g==h term (whole h-tile lies in one segment).
  if ((h0 >> 6) == s) {
#pragma unroll
    for (int h_l = 0; h_l < TH; h_l++) {
      float4 kd = kv[bbase + (size_t)(h0 + h_l) * Wdim + w];
      float pd = fexp2(fmaf(q0[h_l], kd.x, q1[h_l] * kd.y));
      Z [h_l] -= pd;
      nH[h_l] = fmaf(-pd, kd.z, nH[h_l]);
    }
  }
#pragma unroll
  for (int h_l = 0; h_l < TH; h_l++) {
    size_t idx = bbase + (size_t)(h0 + h_l) * Wdim + w;
    part[(size_t)s * BHW + idx] = make_float4(Z[h_l], nH[h_l], nW[h_l], 0.f);
  }
}

// Kernel 3: merge NS partials, finalize, residual add, broadcast 16 channels.
// 2 hw per thread; partials read as dwordx4.
__global__ __launch_bounds__(256) void epi_kernel(
    const float* __restrict__ x, const float4* __restrict__ part,
    const float* __restrict__ gamma, float* __restrict__ out) {
  int idx0 = (blockIdx.x * blockDim.x + threadIdx.x) * 2;
  float Za = 0.f, nHa = 0.f, nWa = 0.f;
  float Zb = 0.f, nHb = 0.f, nWb = 0.f;
#pragma unroll
  for (int s2 = 0; s2 < NS; s2++) {
    float4 pa = part[(size_t)s2 * BHW + idx0];
    float4 pb = part[(size_t)s2 * BHW + idx0 + 1];
    Za += pa.x; nHa += pa.y; nWa += pa.z;
    Zb += pb.x; nHb += pb.y; nWb += pb.z;
  }
  float g = gamma[0];
  float2 sv = make_float2(g * (nHa + nWa) / Za, g * (nHb + nWb) / Zb);
  int b = idx0 >> 16, hw = idx0 & (HW - 1);
  size_t base = (size_t)b * Cch * HW + hw;
#pragma unroll
  for (int c = 0; c < Cch; c++) {
    float2 xv = *(const float2*)&x[base + c * HW];
    *(float2*)&out[base + c * HW] = make_float2(sv.x + xv.x, sv.y + xv.y);
  }
}

extern "C" void kernel_launch(void* const* d_in, const int* in_sizes, int n_in,
                              void* d_out, int out_size, void* d_ws, size_t ws_size,
                              hipStream_t stream) {
  const float* x     = (const float*)d_in[0];
  const float* y     = (const float*)d_in[1];
  const float* Wq    = (const float*)d_in[2];
  const float* bq    = (const float*)d_in[3];
  const float* Wk    = (const float*)d_in[4];
  const float* bk    = (const float*)d_in[5];
  const float* Wv    = (const float*)d_in[6];
  const float* bv    = (const float*)d_in[7];
  const float* gamma = (const float*)d_in[8];
  float* out = (float*)d_out;

  float* ws = (float*)d_ws;
  float2* qpk = (float2*)ws;                  // BHW float2 (1 MB)
  float4* kv  = (float4*)(ws + 2 * BHW);      // BHW float4 (2 MB)
  float4* part = (float4*)(ws + 6 * BHW);     // NS*BHW float4 (8.4 MB)

  qkv_kernel<<<BHW / 512, 256, 0, stream>>>(x, y, Wq, bq, Wk, bk, Wv, bv, qpk, kv);
  attn_kernel<<<Bsz * NHT * NS, 256, 0, stream>>>(qpk, kv, part);
  epi_kernel<<<BHW / 512, 256, 0, stream>>>(x, part, gamma, out);
}

// Round 2
// 125.979 us; speedup vs baseline: 1.0596x; 1.0596x over previous
//
#include <hip/hip_runtime.h>
#include <math.h>

#define Bsz  2
#define Cch  16
#define Hdim 256
#define Wdim 256
#define HW   (Hdim * Wdim)
#define BHW  (Bsz * HW)
#define CctxN 64
#define NS   4            // g-segments
#define SG   (Hdim / NS)  // 64 g values per segment
#define TH   4            // h rows per block (TH=8 regressed: 1 wave/SIMD)
#define NHT  (Hdim / TH)  // 64 h-tiles
#define LOG2E 1.44269504088896340736f

// exp2f lowers to v_exp_f32 on amdgcn (HW exp is base-2).
__device__ __forceinline__ float fexp2(float x) { return exp2f(x); }

// Kernel 1: projections, occupancy-first. Block = 64 pixels x 4 wave-slices.
// Slice s reduces x-channels [4s,4s+4) for q0,q1,k0,k1 and y-channels
// [16s,16s+16) for v; LDS-reduce across slices; wave 0 stores.
// Grid = BHW/64 = 2048 blocks -> 8192 waves (8/SIMD) vs previous 1024 (1/SIMD).
// All loads coalesced: 64 consecutive lanes x 4B per channel plane.
__global__ __launch_bounds__(256) void qkv_kernel(
    const float* __restrict__ x, const float* __restrict__ y,
    const float* __restrict__ Wq, const float* __restrict__ bq,
    const float* __restrict__ Wk, const float* __restrict__ bk,
    const float* __restrict__ Wv, const float* __restrict__ bv,
    float2* __restrict__ qpk, float4* __restrict__ kv) {
  int lane = threadIdx.x & 63;
  int sl   = threadIdx.x >> 6;              // 0..3
  int px   = blockIdx.x * 64 + lane;        // global b*HW + hw
  int b    = px >> 16;
  int hw   = px & (HW - 1);
  const float* xb = x + (size_t)b * Cch * HW + hw;
  const float* yb = y + (size_t)b * CctxN * HW + hw;

  float q0 = 0.f, q1 = 0.f, k0 = 0.f, k1 = 0.f, v = 0.f;
#pragma unroll
  for (int j = 0; j < 4; j++) {
    int c = sl * 4 + j;
    float xv = xb[(size_t)c * HW];
    q0 = fmaf(Wq[c],       xv, q0);
    q1 = fmaf(Wq[Cch + c], xv, q1);
    k0 = fmaf(Wk[c],       xv, k0);
    k1 = fmaf(Wk[Cch + c], xv, k1);
  }
#pragma unroll
  for (int j = 0; j < 16; j++) {
    int c = sl * 16 + j;
    v = fmaf(Wv[c], yb[(size_t)c * HW], v);
  }

  __shared__ float4 lqk[4][64];
  __shared__ float  lv[4][64];
  lqk[sl][lane] = make_float4(q0, q1, k0, k1);
  lv [sl][lane] = v;
  __syncthreads();
  if (sl == 0) {
    float4 a0 = lqk[0][lane], a1 = lqk[1][lane];
    float4 a2 = lqk[2][lane], a3 = lqk[3][lane];
    float vv = lv[0][lane] + lv[1][lane] + lv[2][lane] + lv[3][lane] + bv[0];
    float Q0 = (a0.x + a1.x + a2.x + a3.x + bq[0]) * LOG2E;
    float Q1 = (a0.y + a1.y + a2.y + a3.y + bq[1]) * LOG2E;
    float K0 =  a0.z + a1.z + a2.z + a3.z + bk[0];
    float K1 =  a0.w + a1.w + a2.w + a3.w + bk[1];
    qpk[px] = make_float2(Q0, Q1);
    kv [px] = make_float4(K0, K1, vv, 0.f);
  }
}

// Kernel 2: partial criss-cross softmax sums (no max-sub: scores bounded).
// Block = (b, h-tile of TH=4, g-segment of SG). Thread = w. Diagonal handled
// by post-loop subtraction. Row kv in LDS (broadcast reads). 512 blocks.
__global__ __launch_bounds__(256) void attn_kernel(
    const float2* __restrict__ qpk, const float4* __restrict__ kv,
    float4* __restrict__ part) {
  int s  = blockIdx.x & (NS - 1);
  int ht = (blockIdx.x >> 2) & (NHT - 1);
  int b  = blockIdx.x >> 8;           // 2 (NS) + 6 (NHT) bits
  int w  = threadIdx.x;
  int h0 = ht * TH;
  int g0 = s * SG;
  size_t bbase = (size_t)b * HW;

  __shared__ float4 rowkv[TH][SG];
  {
    int h_l = threadIdx.x >> 6, gg = threadIdx.x & 63;  // TH*SG == 256
    rowkv[h_l][gg] = kv[bbase + (size_t)(h0 + h_l) * Wdim + g0 + gg];
  }
  float q0[TH], q1[TH];
#pragma unroll
  for (int h_l = 0; h_l < TH; h_l++) {
    float2 qq = qpk[bbase + (size_t)(h0 + h_l) * Wdim + w];
    q0[h_l] = qq.x; q1[h_l] = qq.y;
  }
  __syncthreads();

  float Z[TH] = {0,0,0,0}, nH[TH] = {0,0,0,0}, nW[TH] = {0,0,0,0};
#pragma unroll 4
  for (int gg = 0; gg < SG; gg++) {
    float4 kc = kv[bbase + (size_t)(g0 + gg) * Wdim + w];
#pragma unroll
    for (int h_l = 0; h_l < TH; h_l++) {
      float4 r = rowkv[h_l][gg];
      float pH = fexp2(fmaf(q0[h_l], kc.x, q1[h_l] * kc.y));
      float pW = fexp2(fmaf(q0[h_l], r.x,  q1[h_l] * r.y));
      Z [h_l] += pH + pW;
      nH[h_l] = fmaf(pH, kc.z, nH[h_l]);
      nW[h_l] = fmaf(pW, r.z,  nW[h_l]);
    }
  }
  // Diagonal fixup: subtract the g==h term (whole h-tile lies in one segment).
  if ((h0 >> 6) == s) {
#pragma unroll
    for (int h_l = 0; h_l < TH; h_l++) {
      float4 kd = kv[bbase + (size_t)(h0 + h_l) * Wdim + w];
      float pd = fexp2(fmaf(q0[h_l], kd.x, q1[h_l] * kd.y));
      Z [h_l] -= pd;
      nH[h_l] = fmaf(-pd, kd.z, nH[h_l]);
    }
  }
#pragma unroll
  for (int h_l = 0; h_l < TH; h_l++) {
    size_t idx = bbase + (size_t)(h0 + h_l) * Wdim + w;
    part[(size_t)s * BHW + idx] = make_float4(Z[h_l], nH[h_l], nW[h_l], 0.f);
  }
}

// Kernel 3: merge NS partials, finalize, residual add, broadcast 16 channels.
// Occupancy-first: block = 64 pixels x 4 wave-slices; slice s writes channels
// [4s,4s+4). Grid = BHW/64 = 2048 blocks -> 8192 waves (8/SIMD) vs 1024.
// part reads are x4 redundant across slices but L1/L2-resident (8.4 MB).
__global__ __launch_bounds__(256) void epi_kernel(
    const float* __restrict__ x, const float4* __restrict__ part,
    const float* __restrict__ gamma, float* __restrict__ out) {
  int lane = threadIdx.x & 63;
  int sl   = threadIdx.x >> 6;              // 0..3
  int px   = blockIdx.x * 64 + lane;
  float Z = 0.f, nHs = 0.f, nWs = 0.f;
#pragma unroll
  for (int s2 = 0; s2 < NS; s2++) {
    float4 p = part[(size_t)s2 * BHW + px];
    Z += p.x; nHs += p.y; nWs += p.z;
  }
  float sv = gamma[0] * (nHs + nWs) / Z;
  int b = px >> 16, hw = px & (HW - 1);
  size_t base = (size_t)b * Cch * HW + hw;
#pragma unroll
  for (int j = 0; j < 4; j++) {
    int c = sl * 4 + j;
    out[base + (size_t)c * HW] = sv + x[base + (size_t)c * HW];
  }
}

extern "C" void kernel_launch(void* const* d_in, const int* in_sizes, int n_in,
                              void* d_out, int out_size, void* d_ws, size_t ws_size,
                              hipStream_t stream) {
  const float* x     = (const float*)d_in[0];
  const float* y     = (const float*)d_in[1];
  const float* Wq    = (const float*)d_in[2];
  const float* bq    = (const float*)d_in[3];
  const float* Wk    = (const float*)d_in[4];
  const float* bk    = (const float*)d_in[5];
  const float* Wv    = (const float*)d_in[6];
  const float* bv    = (const float*)d_in[7];
  const float* gamma = (const float*)d_in[8];
  float* out = (float*)d_out;

  float* ws = (float*)d_ws;
  float2* qpk = (float2*)ws;                  // BHW float2 (1 MB)
  float4* kv  = (float4*)(ws + 2 * BHW);      // BHW float4 (2 MB)
  float4* part = (float4*)(ws + 6 * BHW);     // NS*BHW float4 (8.4 MB)

  qkv_kernel<<<BHW / 64, 256, 0, stream>>>(x, y, Wq, bq, Wk, bk, Wv, bv, qpk, kv);
  attn_kernel<<<Bsz * NHT * NS, 256, 0, stream>>>(qpk, kv, part);
  epi_kernel<<<BHW / 64, 256, 0, stream>>>(x, part, gamma, out);
}